// Round 1
// baseline (645.636 us; speedup 1.0000x reference)
//
#include <hip/hip_runtime.h>

#define AS1 __attribute__((address_space(1)))
#define AS3 __attribute__((address_space(3)))

typedef __attribute__((ext_vector_type(8))) short s16x8;
typedef __attribute__((ext_vector_type(4))) float f32x4;
typedef __attribute__((ext_vector_type(4))) unsigned short u16x4;

#define MFMA16(a, b, c) __builtin_amdgcn_mfma_f32_16x16x32_bf16(a, b, c, 0, 0, 0)

static __device__ __forceinline__ unsigned short f2bf(float f) {
  unsigned u = __builtin_bit_cast(unsigned, f);
  u += 0x7fffu + ((u >> 16) & 1u);
  return (unsigned short)(u >> 16);
}

static __device__ __forceinline__ void gll16(const unsigned short* g, char* l) {
  __builtin_amdgcn_global_load_lds((const AS1 void*)g, (AS3 void*)l, 16, 0, 0);
}

// ---------------------------------------------------------------------------
// Core: C[128x128] tile of A[M,Kc] @ B[N,Kc]^T, bf16 in, f32 acc.
// A,B tiles staged via global_load_lds (16B), LDS rows 64 elems (128B),
// XOR-swizzled (16B slot ^= row&7) via pre-swizzled global source.
// 4 waves: wave (wm,wn) owns 64x64; 4x4 frags of 16x16; mfma_16x16x32_bf16.
// ---------------------------------------------------------------------------
__device__ __forceinline__ void gemm_tile(const unsigned short* __restrict__ Ab, int lda,
                                          const unsigned short* __restrict__ Bb, int ldb,
                                          int Kc, char* lds, f32x4 (&acc)[4][4]) {
  const int t = threadIdx.x;
  const int lane = t & 63, w = t >> 6, g = lane >> 4, l15 = lane & 15;
  const int wm = w >> 1, wn = w & 1;
  char* As = lds;
  char* Bs = lds + 16384;
  for (int ks = 0; ks < Kc; ks += 64) {
    __syncthreads();  // prior compute done before overwrite
#pragma unroll
    for (int i = 0; i < 4; ++i) {
      const int c = i * 256 + t, row = c >> 3, sl = c & 7;
      const int col = ks + ((sl ^ (row & 7)) << 3);
      const int ubase = (i * 256 + w * 64) << 4;  // wave-uniform LDS byte base
      gll16(Ab + row * lda + col, As + ubase);
      gll16(Bb + row * ldb + col, Bs + ubase);
    }
    __syncthreads();  // compiler drains vmcnt before s_barrier
    s16x8 af[2][4], bfr[2][4];
#pragma unroll
    for (int kk = 0; kk < 2; ++kk)
#pragma unroll
      for (int x4 = 0; x4 < 4; ++x4) {
        const int ra = wm * 64 + x4 * 16 + l15;
        const int rb = wn * 64 + x4 * 16 + l15;
        af[kk][x4] = *(const s16x8*)(As + ra * 128 + ((((kk << 2) + g) ^ (ra & 7)) << 4));
        bfr[kk][x4] = *(const s16x8*)(Bs + rb * 128 + ((((kk << 2) + g) ^ (rb & 7)) << 4));
      }
#pragma unroll
    for (int kk = 0; kk < 2; ++kk)
#pragma unroll
      for (int mt = 0; mt < 4; ++mt)
#pragma unroll
        for (int nt = 0; nt < 4; ++nt)
          acc[mt][nt] = MFMA16(af[kk][mt], bfr[kk][nt], acc[mt][nt]);
  }
}

// ---------------------------------------------------------------------------
// QKV projection: A = x_bf16 [32768,1024], B = Wqkv_t [3072,1024].
// n<1024 -> Q natural [m][n]; else K/V stored TRANSPOSED: T[b][d][s].
// ---------------------------------------------------------------------------
__global__ __launch_bounds__(256) void k_gemm_qkv(const unsigned short* __restrict__ xb,
                                                  const unsigned short* __restrict__ Wt,
                                                  const float* __restrict__ biasq,
                                                  unsigned short* __restrict__ Qb,
                                                  unsigned short* __restrict__ Kt,
                                                  unsigned short* __restrict__ Vt) {
  __shared__ __align__(16) char lds[32768];
  f32x4 acc[4][4];
#pragma unroll
  for (int i = 0; i < 4; ++i)
#pragma unroll
    for (int j = 0; j < 4; ++j) acc[i][j] = f32x4{0.f, 0.f, 0.f, 0.f};
  const int bn = blockIdx.x, bm = blockIdx.y;
  gemm_tile(xb + bm * 128 * 1024, 1024, Wt + bn * 128 * 1024, 1024, 1024, lds, acc);

  const int t = threadIdx.x, lane = t & 63, w = t >> 6, g = lane >> 4, l15 = lane & 15;
  const int wm = w >> 1, wn = w & 1;
  const int nb = bn * 128 + wn * 64, mb = bm * 128 + wm * 64;
#pragma unroll
  for (int nt = 0; nt < 4; ++nt) {
    const int n = nb + nt * 16 + l15;
    const float bias = biasq[n];
#pragma unroll
    for (int mt = 0; mt < 4; ++mt) {
      const int m0 = mb + mt * 16 + g * 4;
      const f32x4 v = acc[mt][nt];
      if (n < 1024) {
#pragma unroll
        for (int r = 0; r < 4; ++r) Qb[(m0 + r) * 1024 + n] = f2bf(v[r] + bias);
      } else {
        unsigned short* T = (n < 2048) ? Kt : Vt;
        const int d = n & 1023;
        const int b = m0 >> 12, s = m0 & 4095;
        u16x4 pk;
#pragma unroll
        for (int r = 0; r < 4; ++r) pk[r] = f2bf(v[r] + bias);
        *(u16x4*)(T + ((b * 1024 + d) * 4096 + s)) = pk;
      }
    }
  }
}

// ---------------------------------------------------------------------------
// Low-rank projections: per (b, kv): C[256,1024] = Et/Ft [256,4096] @ Kt/Vt_b^T.
// kv=0 -> Kp stored natural [kp][d]; kv=1 -> Vp stored transposed [d][kp].
// ---------------------------------------------------------------------------
__global__ __launch_bounds__(256) void k_gemm_kpvp(const unsigned short* __restrict__ Et,
                                                   const unsigned short* __restrict__ Ft,
                                                   const unsigned short* __restrict__ Kt,
                                                   const unsigned short* __restrict__ Vt,
                                                   unsigned short* __restrict__ Kp,
                                                   unsigned short* __restrict__ VpT) {
  __shared__ __align__(16) char lds[32768];
  f32x4 acc[4][4];
#pragma unroll
  for (int i = 0; i < 4; ++i)
#pragma unroll
    for (int j = 0; j < 4; ++j) acc[i][j] = f32x4{0.f, 0.f, 0.f, 0.f};
  const int b = blockIdx.z >> 1, kv = blockIdx.z & 1;
  const unsigned short* Ab = (kv ? Ft : Et) + blockIdx.y * 128 * 4096;
  const unsigned short* Bb = (kv ? Vt : Kt) + b * 4194304 + blockIdx.x * 128 * 4096;
  gemm_tile(Ab, 4096, Bb, 4096, 4096, lds, acc);

  const int t = threadIdx.x, lane = t & 63, w = t >> 6, g = lane >> 4, l15 = lane & 15;
  const int wm = w >> 1, wn = w & 1;
  const int nb = blockIdx.x * 128 + wn * 64, mb = blockIdx.y * 128 + wm * 64;
  if (!kv) {
    unsigned short* C = Kp + b * 262144;
#pragma unroll
    for (int nt = 0; nt < 4; ++nt) {
      const int n = nb + nt * 16 + l15;
#pragma unroll
      for (int mt = 0; mt < 4; ++mt) {
        const int m0 = mb + mt * 16 + g * 4;
        const f32x4 v = acc[mt][nt];
#pragma unroll
        for (int r = 0; r < 4; ++r) C[(m0 + r) * 1024 + n] = f2bf(v[r]);
      }
    }
  } else {
    unsigned short* C = VpT + b * 262144;
#pragma unroll
    for (int nt = 0; nt < 4; ++nt) {
      const int n = nb + nt * 16 + l15;
#pragma unroll
      for (int mt = 0; mt < 4; ++mt) {
        const int m0 = mb + mt * 16 + g * 4;
        const f32x4 v = acc[mt][nt];
        u16x4 pk;
#pragma unroll
        for (int r = 0; r < 4; ++r) pk[r] = f2bf(v[r]);
        *(u16x4*)(C + (n << 8) + m0) = pk;
      }
    }
  }
}

// ---------------------------------------------------------------------------
// Attention over projected length 256. Block = 64 q-rows, 4 waves (16 rows each).
// LDS 48KB: KV region (Kp [256][64] then reused for VpT [64][256]),
// U region (Q-tile [64][64], reused as per-wave P [16][128] halves).
// ---------------------------------------------------------------------------
__global__ __launch_bounds__(256) void k_attn(const unsigned short* __restrict__ Qb,
                                              const unsigned short* __restrict__ Kp,
                                              const unsigned short* __restrict__ VpT,
                                              unsigned short* __restrict__ AO) {
  __shared__ __align__(16) char lds[49152];
  char* KV = lds;           // 32KB
  char* U = lds + 32768;    // 16KB
  const int t = threadIdx.x, lane = t & 63, w = t >> 6, g = lane >> 4, l15 = lane & 15;
  const int s0 = blockIdx.x * 64, h = blockIdx.y, b = blockIdx.z;
  const unsigned short* Qg = Qb + (b * 4096 + s0) * 1024 + h * 64;
  const unsigned short* Kg = Kp + b * 262144 + h * 64;
  const unsigned short* Vg = VpT + b * 262144 + (h * 64) * 256;

#pragma unroll
  for (int i = 0; i < 8; ++i) {  // Kp slice: 256 rows x 128B
    const int c = i * 256 + t, row = c >> 3, sl = c & 7;
    gll16(Kg + row * 1024 + ((sl ^ (row & 7)) << 3), KV + ((i * 256 + w * 64) << 4));
  }
#pragma unroll
  for (int i = 0; i < 2; ++i) {  // Q tile: 64 rows x 128B
    const int c = i * 256 + t, row = c >> 3, sl = c & 7;
    gll16(Qg + row * 1024 + ((sl ^ (row & 7)) << 3), U + ((i * 256 + w * 64) << 4));
  }
  __syncthreads();

  s16x8 aq0, aq1;
  {
    const int row = w * 16 + l15;
    aq0 = *(const s16x8*)(U + row * 128 + ((g ^ (row & 7)) << 4));
    aq1 = *(const s16x8*)(U + row * 128 + (((4 + g) ^ (row & 7)) << 4));
  }
  __syncthreads();  // all waves hold Q frags before U is reused for P

  f32x4 sc[16];
#pragma unroll
  for (int nt = 0; nt < 16; ++nt) sc[nt] = f32x4{0.f, 0.f, 0.f, 0.f};
#pragma unroll
  for (int nt = 0; nt < 16; ++nt) {
    const int row = nt * 16 + l15;
    const s16x8 b0 = *(const s16x8*)(KV + row * 128 + ((g ^ (row & 7)) << 4));
    const s16x8 b1 = *(const s16x8*)(KV + row * 128 + (((4 + g) ^ (row & 7)) << 4));
    sc[nt] = MFMA16(aq0, b0, sc[nt]);
    sc[nt] = MFMA16(aq1, b1, sc[nt]);
  }
  __syncthreads();  // all waves done reading Kp region

  // stage VpT slice [64][256] over the Kp region (async; overlaps softmax)
#pragma unroll
  for (int i = 0; i < 8; ++i) {
    const int c = i * 256 + t, row = c >> 5, sl = c & 31;
    gll16(Vg + row * 256 + ((sl ^ (row & 7)) << 3), KV + ((i * 256 + w * 64) << 4));
  }

  float mx[4], sm[4];
#pragma unroll
  for (int r = 0; r < 4; ++r) {
    float m = sc[0][r];
#pragma unroll
    for (int nt = 1; nt < 16; ++nt) m = fmaxf(m, sc[nt][r]);
    m = fmaxf(m, __shfl_xor(m, 1));
    m = fmaxf(m, __shfl_xor(m, 2));
    m = fmaxf(m, __shfl_xor(m, 4));
    m = fmaxf(m, __shfl_xor(m, 8));
    mx[r] = m;
    sm[r] = 0.f;
  }
  const float SC = 0.125f * 1.4426950408889634f;  // log2e / sqrt(DK)
  char* Pw = U + (w << 12);  // per-wave P slab [16][256B]
  f32x4 ov[4];
#pragma unroll
  for (int nt = 0; nt < 4; ++nt) ov[nt] = f32x4{0.f, 0.f, 0.f, 0.f};

  // half 0: P writes (k 0..127)
#pragma unroll
  for (int nt2 = 0; nt2 < 8; ++nt2) {
#pragma unroll
    for (int r = 0; r < 4; ++r) {
      const float p = exp2f((sc[nt2][r] - mx[r]) * SC);
      sm[r] += p;
      const int row = g * 4 + r;
      *(unsigned short*)(Pw + row * 256 + (((nt2 * 16 + l15) << 1) ^ ((row & 7) << 4))) = f2bf(p);
    }
  }
  __syncthreads();  // VpT staged (vmcnt drained before barrier)

#pragma unroll
  for (int half = 0; half < 2; ++half) {
    if (half == 1) {
#pragma unroll
      for (int nt2 = 0; nt2 < 8; ++nt2) {
#pragma unroll
        for (int r = 0; r < 4; ++r) {
          const float p = exp2f((sc[8 + nt2][r] - mx[r]) * SC);
          sm[r] += p;
          const int row = g * 4 + r;
          *(unsigned short*)(Pw + row * 256 + (((nt2 * 16 + l15) << 1) ^ ((row & 7) << 4))) = f2bf(p);
        }
      }
    }
#pragma unroll
    for (int kk = 0; kk < 4; ++kk) {
      const int rp = l15;
      const s16x8 ap = *(const s16x8*)(Pw + rp * 256 + ((((kk << 2) + g) ^ (rp & 7)) << 4));
#pragma unroll
      for (int nt = 0; nt < 4; ++nt) {
        const int rv = nt * 16 + l15;
        const int slot = half * 16 + (kk << 2) + g;
        const s16x8 bv = *(const s16x8*)(KV + rv * 512 + ((slot ^ (rv & 7)) << 4));
        ov[nt] = MFMA16(ap, bv, ov[nt]);
      }
    }
  }
#pragma unroll
  for (int r = 0; r < 4; ++r) {
    float s = sm[r];
    s += __shfl_xor(s, 1);
    s += __shfl_xor(s, 2);
    s += __shfl_xor(s, 4);
    s += __shfl_xor(s, 8);
    sm[r] = 1.f / s;
  }
  unsigned short* Ao = AO + (b * 4096 + s0 + w * 16) * 1024 + h * 64;
#pragma unroll
  for (int nt = 0; nt < 4; ++nt) {
#pragma unroll
    for (int r = 0; r < 4; ++r) {
      Ao[(g * 4 + r) * 1024 + nt * 16 + l15] = f2bf(ov[nt][r] * sm[r]);
    }
  }
}

// ---------------------------------------------------------------------------
// Output projection: f32 out = AO_bf16 @ Wo^T + bo
// ---------------------------------------------------------------------------
__global__ __launch_bounds__(256) void k_gemm_out(const unsigned short* __restrict__ AO,
                                                  const unsigned short* __restrict__ Wot,
                                                  const float* __restrict__ bo,
                                                  float* __restrict__ out) {
  __shared__ __align__(16) char lds[32768];
  f32x4 acc[4][4];
#pragma unroll
  for (int i = 0; i < 4; ++i)
#pragma unroll
    for (int j = 0; j < 4; ++j) acc[i][j] = f32x4{0.f, 0.f, 0.f, 0.f};
  const int bn = blockIdx.x, bm = blockIdx.y;
  gemm_tile(AO + bm * 128 * 1024, 1024, Wot + bn * 128 * 1024, 1024, 1024, lds, acc);

  const int t = threadIdx.x, lane = t & 63, w = t >> 6, g = lane >> 4, l15 = lane & 15;
  const int wm = w >> 1, wn = w & 1;
  const int nb = bn * 128 + wn * 64, mb = bm * 128 + wm * 64;
#pragma unroll
  for (int nt = 0; nt < 4; ++nt) {
    const int n = nb + nt * 16 + l15;
    const float bias = bo[n];
#pragma unroll
    for (int mt = 0; mt < 4; ++mt) {
      const int m0 = mb + mt * 16 + g * 4;
      const f32x4 v = acc[mt][nt];
#pragma unroll
      for (int r = 0; r < 4; ++r) out[(m0 + r) * 1024 + n] = v[r] + bias;
    }
  }
}

// ---------------------------------------------------------------------------
// Converters
// ---------------------------------------------------------------------------
__global__ __launch_bounds__(256) void k_cvt_x(const float* __restrict__ x,
                                               unsigned short* __restrict__ xb) {
  const int i = (blockIdx.x * 256 + threadIdx.x) * 4;
  const float4 v = *(const float4*)(x + i);
  u16x4 o;
  o[0] = f2bf(v.x);
  o[1] = f2bf(v.y);
  o[2] = f2bf(v.z);
  o[3] = f2bf(v.w);
  *(u16x4*)(xb + i) = o;
}

__global__ __launch_bounds__(256) void k_prep(const float* __restrict__ Wq, const float* __restrict__ Wk,
                                              const float* __restrict__ Wv, const float* __restrict__ Wo,
                                              const float* __restrict__ E, const float* __restrict__ Fp,
                                              const float* __restrict__ bq, const float* __restrict__ bk,
                                              const float* __restrict__ bv,
                                              unsigned short* __restrict__ Wqkvt, unsigned short* __restrict__ Wot,
                                              unsigned short* __restrict__ Et, unsigned short* __restrict__ Ft,
                                              float* __restrict__ biasq) {
  const int i = blockIdx.x * 256 + threadIdx.x;
  if (i < 3145728) {  // Wq|Wk|Wv transposed: Wqkvt[g][n][k] = Wg[k][n]
    const int gsel = i >> 20, rem = i & 1048575, n = rem >> 10, k = rem & 1023;
    const float* W = gsel == 0 ? Wq : (gsel == 1 ? Wk : Wv);
    Wqkvt[i] = f2bf(W[(k << 10) + n]);
  } else if (i < 4194304) {
    const int j = i - 3145728, n = j >> 10, k = j & 1023;
    Wot[j] = f2bf(Wo[(k << 10) + n]);
  } else if (i < 5242880) {  // Et[kp][s] = E[s][kp]
    const int j = i - 4194304, kp = j >> 12, s = j & 4095;
    Et[j] = f2bf(E[(s << 8) + kp]);
  } else if (i < 6291456) {
    const int j = i - 5242880, kp = j >> 12, s = j & 4095;
    Ft[j] = f2bf(Fp[(s << 8) + kp]);
  } else if (i < 6294528) {
    const int j = i - 6291456;
    biasq[j] = (j < 1024) ? bq[j] : (j < 2048 ? bk[j - 1024] : bv[j - 2048]);
  }
}

// ---------------------------------------------------------------------------
extern "C" void kernel_launch(void* const* d_in, const int* in_sizes, int n_in,
                              void* d_out, int out_size, void* d_ws, size_t ws_size,
                              hipStream_t stream) {
  const float* x = (const float*)d_in[0];
  const float* Wq = (const float*)d_in[1];
  const float* bq = (const float*)d_in[2];
  const float* Wk = (const float*)d_in[3];
  const float* bk = (const float*)d_in[4];
  const float* Wv = (const float*)d_in[5];
  const float* bv = (const float*)d_in[6];
  const float* Wo = (const float*)d_in[7];
  const float* bo = (const float*)d_in[8];
  const float* E = (const float*)d_in[9];
  const float* Fp = (const float*)d_in[10];

  char* ws = (char*)d_ws;
  size_t off = 0;
  auto alloc = [&](size_t bytes) {
    char* p = ws + off;
    off += (bytes + 255) & ~(size_t)255;
    return p;
  };
  unsigned short* xb = (unsigned short*)alloc(33554432ull * 2);   // x bf16; later reused as attn-out
  unsigned short* Qb = (unsigned short*)alloc(33554432ull * 2);   // Q [32768][1024]
  unsigned short* Kt = (unsigned short*)alloc(33554432ull * 2);   // K^T [b][1024][4096]
  unsigned short* Vt = (unsigned short*)alloc(33554432ull * 2);   // V^T [b][1024][4096]
  unsigned short* Wqkvt = (unsigned short*)alloc(3145728ull * 2); // [3072][1024]
  unsigned short* Wot = (unsigned short*)alloc(1048576ull * 2);
  unsigned short* Et = (unsigned short*)alloc(1048576ull * 2);    // [256][4096]
  unsigned short* Ft = (unsigned short*)alloc(1048576ull * 2);
  unsigned short* Kp = (unsigned short*)alloc(2097152ull * 2);    // [b][256][1024]
  unsigned short* VpT = (unsigned short*)alloc(2097152ull * 2);   // [b][1024][256]
  float* biasq = (float*)alloc(3072 * 4);
  (void)in_sizes; (void)n_in; (void)out_size; (void)ws_size;

  k_cvt_x<<<32768, 256, 0, stream>>>(x, xb);
  k_prep<<<24588, 256, 0, stream>>>(Wq, Wk, Wv, Wo, E, Fp, bq, bk, bv, Wqkvt, Wot, Et, Ft, biasq);
  k_gemm_qkv<<<dim3(24, 256), 256, 0, stream>>>(xb, Wqkvt, biasq, Qb, Kt, Vt);
  k_gemm_kpvp<<<dim3(8, 2, 16), 256, 0, stream>>>(Et, Ft, Kt, Vt, Kp, VpT);
  k_attn<<<dim3(64, 16, 8), 256, 0, stream>>>(Qb, Kp, VpT, xb);
  k_gemm_out<<<dim3(8, 256), 256, 0, stream>>>(xb, Wot, bo, (float*)d_out);
}

// Round 2
// 561.933 us; speedup vs baseline: 1.1490x; 1.1490x over previous
//
#include <hip/hip_runtime.h>

#define AS1 __attribute__((address_space(1)))
#define AS3 __attribute__((address_space(3)))

typedef __attribute__((ext_vector_type(8))) short s16x8;
typedef __attribute__((ext_vector_type(4))) float f32x4;
typedef __attribute__((ext_vector_type(4))) unsigned short u16x4;

#define MFMA16(a, b, c) __builtin_amdgcn_mfma_f32_16x16x32_bf16(a, b, c, 0, 0, 0)

static __device__ __forceinline__ unsigned short f2bf(float f) {
  unsigned u = __builtin_bit_cast(unsigned, f);
  u += 0x7fffu + ((u >> 16) & 1u);
  return (unsigned short)(u >> 16);
}

static __device__ __forceinline__ void gll16(const unsigned short* g, char* l) {
  __builtin_amdgcn_global_load_lds((const AS1 void*)g, (AS3 void*)l, 16, 0, 0);
}

#define BAR() asm volatile("s_barrier" ::: "memory")
#define WAITV(N) asm volatile("s_waitcnt vmcnt(" #N ")" ::: "memory")

// ===========================================================================
// 256x256 8-phase pipelined GEMM core (C = A[M,K] @ B[N,K]^T), bf16, f32 acc.
// 512 threads = 8 waves (2M x 4N), per-wave C = 128x64 (acc[8][4] frags).
// LDS 128KB: double-buffered A[256][64] + B[256][64], rows 128B,
// 16B-slot XOR swizzle (slot ^= row&7) via pre-swizzled global source.
// Counted vmcnt(4) at phases 4/8 only; raw s_barrier (no drain).
// ===========================================================================
__device__ __forceinline__ void gemm256_pipe(const unsigned short* __restrict__ A0, int lda,
                                             const unsigned short* __restrict__ B0, int ldb,
                                             int NT2, char* lds, f32x4 (&acc)[8][4]) {
  const int t = threadIdx.x;
  const int lane = t & 63, w = t >> 6, g = lane >> 4, l15 = lane & 15;
  const int wm = w >> 2, wn = w & 3;
  char* const A_lds[2] = {lds, lds + 65536};
  char* const B_lds[2] = {lds + 32768, lds + 98304};
  s16x8 af[2][4], bfr[2][4];

#define STG(SRC, LD, KS, DST, H)                                                         \
  do {                                                                                   \
    _Pragma("unroll") for (int j = 0; j < 2; ++j) {                                      \
      const int flat = j * 512 + t;                                                      \
      const int rl = flat >> 3, sl = flat & 7;                                           \
      gll16((SRC) + (size_t)((H)*128 + rl) * (LD) + (KS) + ((sl ^ (rl & 7)) << 3),       \
            (DST) + (((H)*1024 + j * 512 + w * 64) << 4));                               \
    }                                                                                    \
  } while (0)

#define LDAQ(BUF, QH)                                                                    \
  do {                                                                                   \
    _Pragma("unroll") for (int mi = 0; mi < 4; ++mi) {                                   \
      const int row = wm * 128 + (QH)*64 + mi * 16 + l15;                                \
      _Pragma("unroll") for (int kk = 0; kk < 2; ++kk)                                   \
          af[kk][mi] = *(const s16x8*)(A_lds[BUF] + row * 128 +                          \
                                       (((kk * 4 + g) ^ (row & 7)) << 4));               \
    }                                                                                    \
  } while (0)

#define LDBP(BUF, NH)                                                                    \
  do {                                                                                   \
    _Pragma("unroll") for (int ni = 0; ni < 2; ++ni) {                                   \
      const int row = wn * 64 + ((NH)*2 + ni) * 16 + l15;                                \
      _Pragma("unroll") for (int kk = 0; kk < 2; ++kk)                                   \
          bfr[kk][(NH)*2 + ni] = *(const s16x8*)(B_lds[BUF] + row * 128 +                \
                                                 (((kk * 4 + g) ^ (row & 7)) << 4));     \
    }                                                                                    \
  } while (0)

#define MQUAD(QH, NH)                                                                    \
  do {                                                                                   \
    __builtin_amdgcn_s_setprio(1);                                                       \
    _Pragma("unroll") for (int kk = 0; kk < 2; ++kk)                                     \
        _Pragma("unroll") for (int mi = 0; mi < 4; ++mi)                                 \
            _Pragma("unroll") for (int ni = 0; ni < 2; ++ni)                             \
                acc[(QH)*4 + mi][(NH)*2 + ni] =                                          \
        MFMA16(af[kk][mi], bfr[kk][(NH)*2 + ni], acc[(QH)*4 + mi][(NH)*2 + ni]);         \
    __builtin_amdgcn_s_setprio(0);                                                       \
  } while (0)

  // prologue: T0 fully, T1.B halves
  STG(A0, lda, 0, A_lds[0], 0);
  STG(A0, lda, 0, A_lds[0], 1);
  STG(B0, ldb, 0, B_lds[0], 0);
  STG(B0, ldb, 0, B_lds[0], 1);
  STG(B0, ldb, 64, B_lds[1], 0);
  STG(B0, ldb, 64, B_lds[1], 1);
  WAITV(4);
  BAR();

  for (int it = 0; it < NT2; ++it) {
    const int kT1 = it * 128 + 64;
    const int kT2 = it * 128 + 128;
    const bool pf = (it + 1 < NT2);
    // p1: Q(0,0) on buf0; stage T1.A-lo -> buf1 (last read prev p7)
    LDAQ(0, 0);
    LDBP(0, 0);
    STG(A0, lda, kT1, A_lds[1], 0);
    BAR();
    MQUAD(0, 0);
    BAR();
    // p2: Q(0,1); stage T1.A-hi
    LDBP(0, 1);
    STG(A0, lda, kT1, A_lds[1], 1);
    BAR();
    MQUAD(0, 1);
    BAR();
    // p3: Q(1,0); stage T2.B-lo -> buf0 (B last read p2)
    LDAQ(0, 1);
    if (pf) STG(B0, ldb, kT2, B_lds[0], 0);
    BAR();
    MQUAD(1, 0);
    BAR();
    // p4: Q(1,1); stage T2.B-hi; guard T1.A landed
    if (pf) STG(B0, ldb, kT2, B_lds[0], 1);
    BAR();
    MQUAD(1, 1);
    if (pf) WAITV(4);
    else WAITV(0);
    BAR();
    // p5: Q(0,0) on buf1; stage T2.A-lo -> buf0 (A last read p3)
    LDAQ(1, 0);
    LDBP(1, 0);
    if (pf) STG(A0, lda, kT2, A_lds[0], 0);
    BAR();
    MQUAD(0, 0);
    BAR();
    // p6: Q(0,1); stage T2.A-hi
    LDBP(1, 1);
    if (pf) STG(A0, lda, kT2, A_lds[0], 1);
    BAR();
    MQUAD(0, 1);
    BAR();
    // p7: Q(1,0); stage T3.B-lo -> buf1 (B last read p6)
    LDAQ(1, 1);
    if (pf) STG(B0, ldb, kT2 + 64, B_lds[1], 0);
    BAR();
    MQUAD(1, 0);
    BAR();
    // p8: Q(1,1); stage T3.B-hi; guard T2.A landed
    if (pf) STG(B0, ldb, kT2 + 64, B_lds[1], 1);
    BAR();
    MQUAD(1, 1);
    if (pf) WAITV(4);
    BAR();
  }
#undef STG
#undef LDAQ
#undef LDBP
#undef MQUAD
}

// ---------------------------------------------------------------------------
// QKV projection (8-phase 256^2): A = x_bf16 [32768,1024], B = Wqkv_t [3072,1024].
// n<1024 -> Q natural [m][n]; else K/V stored TRANSPOSED: T[b][d][s].
// ---------------------------------------------------------------------------
__global__ __launch_bounds__(512, 2) void k_gemm_qkv(const unsigned short* __restrict__ xb,
                                                     const unsigned short* __restrict__ Wt,
                                                     const float* __restrict__ biasq,
                                                     unsigned short* __restrict__ Qb,
                                                     unsigned short* __restrict__ Kt,
                                                     unsigned short* __restrict__ Vt) {
  __shared__ __align__(16) char lds[131072];
  f32x4 acc[8][4];
#pragma unroll
  for (int i = 0; i < 8; ++i)
#pragma unroll
    for (int j = 0; j < 4; ++j) acc[i][j] = f32x4{0.f, 0.f, 0.f, 0.f};
  // XCD-aware swizzle (nwg = 1536, %8 == 0)
  int bid = blockIdx.y * 12 + blockIdx.x;
  bid = (bid & 7) * 192 + (bid >> 3);
  const int bn = bid % 12, bm = bid / 12;
  gemm256_pipe(xb + (size_t)bm * 256 * 1024, 1024, Wt + (size_t)bn * 256 * 1024, 1024, 8, lds, acc);

  const int t = threadIdx.x, lane = t & 63, w = t >> 6, g = lane >> 4, l15 = lane & 15;
  const int wm = w >> 2, wn = w & 3;
  const int mbase = bm * 256 + wm * 128, nbase = bn * 256 + wn * 64;
#pragma unroll
  for (int nf = 0; nf < 4; ++nf) {
    const int n = nbase + nf * 16 + l15;
    const float bias = biasq[n];
#pragma unroll
    for (int mq = 0; mq < 8; ++mq) {
      const int m0 = mbase + mq * 16 + g * 4;
      const f32x4 v = acc[mq][nf];
      if (n < 1024) {
#pragma unroll
        for (int r = 0; r < 4; ++r) Qb[(size_t)(m0 + r) * 1024 + n] = f2bf(v[r] + bias);
      } else {
        unsigned short* T = (n < 2048) ? Kt : Vt;
        const int d = n & 1023;
        const int b = m0 >> 12, s = m0 & 4095;
        u16x4 pk;
#pragma unroll
        for (int r = 0; r < 4; ++r) pk[r] = f2bf(v[r] + bias);
        *(u16x4*)(T + ((size_t)(b * 1024 + d) * 4096 + s)) = pk;
      }
    }
  }
}

// ---------------------------------------------------------------------------
// Output projection (8-phase 256^2): f32 out = AO_bf16 @ Wo^T + bo
// ---------------------------------------------------------------------------
__global__ __launch_bounds__(512, 2) void k_gemm_out(const unsigned short* __restrict__ AO,
                                                     const unsigned short* __restrict__ Wot,
                                                     const float* __restrict__ bo,
                                                     float* __restrict__ out) {
  __shared__ __align__(16) char lds[131072];
  f32x4 acc[8][4];
#pragma unroll
  for (int i = 0; i < 8; ++i)
#pragma unroll
    for (int j = 0; j < 4; ++j) acc[i][j] = f32x4{0.f, 0.f, 0.f, 0.f};
  int bid = blockIdx.y * 4 + blockIdx.x;  // nwg = 512
  bid = (bid & 7) * 64 + (bid >> 3);
  const int bn = bid & 3, bm = bid >> 2;
  gemm256_pipe(AO + (size_t)bm * 256 * 1024, 1024, Wot + (size_t)bn * 256 * 1024, 1024, 8, lds, acc);

  const int t = threadIdx.x, lane = t & 63, w = t >> 6, g = lane >> 4, l15 = lane & 15;
  const int wm = w >> 2, wn = w & 3;
  const int mbase = bm * 256 + wm * 128, nbase = bn * 256 + wn * 64;
#pragma unroll
  for (int nf = 0; nf < 4; ++nf) {
    const int n = nbase + nf * 16 + l15;
    const float bias = bo[n];
#pragma unroll
    for (int mq = 0; mq < 8; ++mq) {
      const int m0 = mbase + mq * 16 + g * 4;
      const f32x4 v = acc[mq][nf];
#pragma unroll
      for (int r = 0; r < 4; ++r) out[(size_t)(m0 + r) * 1024 + n] = v[r] + bias;
    }
  }
}

// ===========================================================================
// 128x128 2-barrier GEMM core (kept for the small-M low-rank projections)
// ===========================================================================
__device__ __forceinline__ void gemm_tile(const unsigned short* __restrict__ Ab, int lda,
                                          const unsigned short* __restrict__ Bb, int ldb,
                                          int Kc, char* lds, f32x4 (&acc)[4][4]) {
  const int t = threadIdx.x;
  const int lane = t & 63, w = t >> 6, g = lane >> 4, l15 = lane & 15;
  const int wm = w >> 1, wn = w & 1;
  char* As = lds;
  char* Bs = lds + 16384;
  for (int ks = 0; ks < Kc; ks += 64) {
    __syncthreads();
#pragma unroll
    for (int i = 0; i < 4; ++i) {
      const int c = i * 256 + t, row = c >> 3, sl = c & 7;
      const int col = ks + ((sl ^ (row & 7)) << 3);
      const int ubase = (i * 256 + w * 64) << 4;
      gll16(Ab + (size_t)row * lda + col, As + ubase);
      gll16(Bb + (size_t)row * ldb + col, Bs + ubase);
    }
    __syncthreads();
    s16x8 af[2][4], bfr[2][4];
#pragma unroll
    for (int kk = 0; kk < 2; ++kk)
#pragma unroll
      for (int x4 = 0; x4 < 4; ++x4) {
        const int ra = wm * 64 + x4 * 16 + l15;
        const int rb = wn * 64 + x4 * 16 + l15;
        af[kk][x4] = *(const s16x8*)(As + ra * 128 + ((((kk << 2) + g) ^ (ra & 7)) << 4));
        bfr[kk][x4] = *(const s16x8*)(Bs + rb * 128 + ((((kk << 2) + g) ^ (rb & 7)) << 4));
      }
#pragma unroll
    for (int kk = 0; kk < 2; ++kk)
#pragma unroll
      for (int mt = 0; mt < 4; ++mt)
#pragma unroll
        for (int nt = 0; nt < 4; ++nt)
          acc[mt][nt] = MFMA16(af[kk][mt], bfr[kk][nt], acc[mt][nt]);
  }
}

// ---------------------------------------------------------------------------
// Low-rank projections: per (b, kv): C[256,1024] = Et/Ft [256,4096] @ Kt/Vt_b^T.
// kv=0 -> Kp natural [kp][d]; kv=1 -> Vp stored transposed [d][kp].
// ---------------------------------------------------------------------------
__global__ __launch_bounds__(256) void k_gemm_kpvp(const unsigned short* __restrict__ Et,
                                                   const unsigned short* __restrict__ Ft,
                                                   const unsigned short* __restrict__ Kt,
                                                   const unsigned short* __restrict__ Vt,
                                                   unsigned short* __restrict__ Kp,
                                                   unsigned short* __restrict__ VpT) {
  __shared__ __align__(16) char lds[32768];
  f32x4 acc[4][4];
#pragma unroll
  for (int i = 0; i < 4; ++i)
#pragma unroll
    for (int j = 0; j < 4; ++j) acc[i][j] = f32x4{0.f, 0.f, 0.f, 0.f};
  const int b = blockIdx.z >> 1, kv = blockIdx.z & 1;
  const unsigned short* Ab = (kv ? Ft : Et) + blockIdx.y * 128 * 4096;
  const unsigned short* Bb = (kv ? Vt : Kt) + (size_t)b * 4194304 + blockIdx.x * 128 * 4096;
  gemm_tile(Ab, 4096, Bb, 4096, 4096, lds, acc);

  const int t = threadIdx.x, lane = t & 63, w = t >> 6, g = lane >> 4, l15 = lane & 15;
  const int wm = w >> 1, wn = w & 1;
  const int nb = blockIdx.x * 128 + wn * 64, mb = blockIdx.y * 128 + wm * 64;
  if (!kv) {
    unsigned short* C = Kp + b * 262144;
#pragma unroll
    for (int nt = 0; nt < 4; ++nt) {
      const int n = nb + nt * 16 + l15;
#pragma unroll
      for (int mt = 0; mt < 4; ++mt) {
        const int m0 = mb + mt * 16 + g * 4;
        const f32x4 v = acc[mt][nt];
#pragma unroll
        for (int r = 0; r < 4; ++r) C[(m0 + r) * 1024 + n] = f2bf(v[r]);
      }
    }
  } else {
    unsigned short* C = VpT + b * 262144;
#pragma unroll
    for (int nt = 0; nt < 4; ++nt) {
      const int n = nb + nt * 16 + l15;
#pragma unroll
      for (int mt = 0; mt < 4; ++mt) {
        const int m0 = mb + mt * 16 + g * 4;
        const f32x4 v = acc[mt][nt];
        u16x4 pk;
#pragma unroll
        for (int r = 0; r < 4; ++r) pk[r] = f2bf(v[r]);
        *(u16x4*)(C + (n << 8) + m0) = pk;
      }
    }
  }
}

// ---------------------------------------------------------------------------
// Attention over projected length 256. Block = 64 q-rows, 4 waves (16 rows each).
// ---------------------------------------------------------------------------
__global__ __launch_bounds__(256) void k_attn(const unsigned short* __restrict__ Qb,
                                              const unsigned short* __restrict__ Kp,
                                              const unsigned short* __restrict__ VpT,
                                              unsigned short* __restrict__ AO) {
  __shared__ __align__(16) char lds[49152];
  char* KV = lds;
  char* U = lds + 32768;
  const int t = threadIdx.x, lane = t & 63, w = t >> 6, g = lane >> 4, l15 = lane & 15;
  const int s0 = blockIdx.x * 64, h = blockIdx.y, b = blockIdx.z;
  const unsigned short* Qg = Qb + (size_t)(b * 4096 + s0) * 1024 + h * 64;
  const unsigned short* Kg = Kp + b * 262144 + h * 64;
  const unsigned short* Vg = VpT + b * 262144 + (h * 64) * 256;

#pragma unroll
  for (int i = 0; i < 8; ++i) {
    const int c = i * 256 + t, row = c >> 3, sl = c & 7;
    gll16(Kg + row * 1024 + ((sl ^ (row & 7)) << 3), KV + ((i * 256 + w * 64) << 4));
  }
#pragma unroll
  for (int i = 0; i < 2; ++i) {
    const int c = i * 256 + t, row = c >> 3, sl = c & 7;
    gll16(Qg + row * 1024 + ((sl ^ (row & 7)) << 3), U + ((i * 256 + w * 64) << 4));
  }
  __syncthreads();

  s16x8 aq0, aq1;
  {
    const int row = w * 16 + l15;
    aq0 = *(const s16x8*)(U + row * 128 + ((g ^ (row & 7)) << 4));
    aq1 = *(const s16x8*)(U + row * 128 + (((4 + g) ^ (row & 7)) << 4));
  }
  __syncthreads();

  f32x4 sc[16];
#pragma unroll
  for (int nt = 0; nt < 16; ++nt) sc[nt] = f32x4{0.f, 0.f, 0.f, 0.f};
#pragma unroll
  for (int nt = 0; nt < 16; ++nt) {
    const int row = nt * 16 + l15;
    const s16x8 b0 = *(const s16x8*)(KV + row * 128 + ((g ^ (row & 7)) << 4));
    const s16x8 b1 = *(const s16x8*)(KV + row * 128 + (((4 + g) ^ (row & 7)) << 4));
    sc[nt] = MFMA16(aq0, b0, sc[nt]);
    sc[nt] = MFMA16(aq1, b1, sc[nt]);
  }
  __syncthreads();

#pragma unroll
  for (int i = 0; i < 8; ++i) {
    const int c = i * 256 + t, row = c >> 5, sl = c & 31;
    gll16(Vg + row * 256 + ((sl ^ (row & 7)) << 3), KV + ((i * 256 + w * 64) << 4));
  }

  float mx[4], sm[4];
#pragma unroll
  for (int r = 0; r < 4; ++r) {
    float m = sc[0][r];
#pragma unroll
    for (int nt = 1; nt < 16; ++nt) m = fmaxf(m, sc[nt][r]);
    m = fmaxf(m, __shfl_xor(m, 1));
    m = fmaxf(m, __shfl_xor(m, 2));
    m = fmaxf(m, __shfl_xor(m, 4));
    m = fmaxf(m, __shfl_xor(m, 8));
    mx[r] = m;
    sm[r] = 0.f;
  }
  const float SC = 0.125f * 1.4426950408889634f;
  char* Pw = U + (w << 12);
  f32x4 ov[4];
#pragma unroll
  for (int nt = 0; nt < 4; ++nt) ov[nt] = f32x4{0.f, 0.f, 0.f, 0.f};

#pragma unroll
  for (int nt2 = 0; nt2 < 8; ++nt2) {
#pragma unroll
    for (int r = 0; r < 4; ++r) {
      const float p = exp2f((sc[nt2][r] - mx[r]) * SC);
      sm[r] += p;
      const int row = g * 4 + r;
      *(unsigned short*)(Pw + row * 256 + (((nt2 * 16 + l15) << 1) ^ ((row & 7) << 4))) = f2bf(p);
    }
  }
  __syncthreads();

#pragma unroll
  for (int half = 0; half < 2; ++half) {
    if (half == 1) {
#pragma unroll
      for (int nt2 = 0; nt2 < 8; ++nt2) {
#pragma unroll
        for (int r = 0; r < 4; ++r) {
          const float p = exp2f((sc[8 + nt2][r] - mx[r]) * SC);
          sm[r] += p;
          const int row = g * 4 + r;
          *(unsigned short*)(Pw + row * 256 + (((nt2 * 16 + l15) << 1) ^ ((row & 7) << 4))) = f2bf(p);
        }
      }
    }
#pragma unroll
    for (int kk = 0; kk < 4; ++kk) {
      const int rp = l15;
      const s16x8 ap = *(const s16x8*)(Pw + rp * 256 + ((((kk << 2) + g) ^ (rp & 7)) << 4));
#pragma unroll
      for (int nt = 0; nt < 4; ++nt) {
        const int rv = nt * 16 + l15;
        const int slot = half * 16 + (kk << 2) + g;
        const s16x8 bv = *(const s16x8*)(KV + rv * 512 + ((slot ^ (rv & 7)) << 4));
        ov[nt] = MFMA16(ap, bv, ov[nt]);
      }
    }
  }
#pragma unroll
  for (int r = 0; r < 4; ++r) {
    float s = sm[r];
    s += __shfl_xor(s, 1);
    s += __shfl_xor(s, 2);
    s += __shfl_xor(s, 4);
    s += __shfl_xor(s, 8);
    sm[r] = 1.f / s;
  }
  unsigned short* Ao = AO + (size_t)(b * 4096 + s0 + w * 16) * 1024 + h * 64;
#pragma unroll
  for (int nt = 0; nt < 4; ++nt) {
#pragma unroll
    for (int r = 0; r < 4; ++r) {
      Ao[(g * 4 + r) * 1024 + nt * 16 + l15] = f2bf(ov[nt][r] * sm[r]);
    }
  }
}

// ---------------------------------------------------------------------------
// Converters
// ---------------------------------------------------------------------------
__global__ __launch_bounds__(256) void k_cvt_x(const float* __restrict__ x,
                                               unsigned short* __restrict__ xb) {
  const int i = (blockIdx.x * 256 + threadIdx.x) * 4;
  const float4 v = *(const float4*)(x + i);
  u16x4 o;
  o[0] = f2bf(v.x);
  o[1] = f2bf(v.y);
  o[2] = f2bf(v.z);
  o[3] = f2bf(v.w);
  *(u16x4*)(xb + i) = o;
}

__global__ __launch_bounds__(256) void k_prep(const float* __restrict__ Wq, const float* __restrict__ Wk,
                                              const float* __restrict__ Wv, const float* __restrict__ Wo,
                                              const float* __restrict__ E, const float* __restrict__ Fp,
                                              const float* __restrict__ bq, const float* __restrict__ bk,
                                              const float* __restrict__ bv,
                                              unsigned short* __restrict__ Wqkvt, unsigned short* __restrict__ Wot,
                                              unsigned short* __restrict__ Et, unsigned short* __restrict__ Ft,
                                              float* __restrict__ biasq) {
  const int i = blockIdx.x * 256 + threadIdx.x;
  if (i < 3145728) {
    const int gsel = i >> 20, rem = i & 1048575, n = rem >> 10, k = rem & 1023;
    const float* W = gsel == 0 ? Wq : (gsel == 1 ? Wk : Wv);
    Wqkvt[i] = f2bf(W[(k << 10) + n]);
  } else if (i < 4194304) {
    const int j = i - 3145728, n = j >> 10, k = j & 1023;
    Wot[j] = f2bf(Wo[(k << 10) + n]);
  } else if (i < 5242880) {
    const int j = i - 4194304, kp = j >> 12, s = j & 4095;
    Et[j] = f2bf(E[(s << 8) + kp]);
  } else if (i < 6291456) {
    const int j = i - 5242880, kp = j >> 12, s = j & 4095;
    Ft[j] = f2bf(Fp[(s << 8) + kp]);
  } else if (i < 6294528) {
    const int j = i - 6291456;
    biasq[j] = (j < 1024) ? bq[j] : (j < 2048 ? bk[j - 1024] : bv[j - 2048]);
  }
}

// ---------------------------------------------------------------------------
extern "C" void kernel_launch(void* const* d_in, const int* in_sizes, int n_in,
                              void* d_out, int out_size, void* d_ws, size_t ws_size,
                              hipStream_t stream) {
  const float* x = (const float*)d_in[0];
  const float* Wq = (const float*)d_in[1];
  const float* bq = (const float*)d_in[2];
  const float* Wk = (const float*)d_in[3];
  const float* bk = (const float*)d_in[4];
  const float* Wv = (const float*)d_in[5];
  const float* bv = (const float*)d_in[6];
  const float* Wo = (const float*)d_in[7];
  const float* bo = (const float*)d_in[8];
  const float* E = (const float*)d_in[9];
  const float* Fp = (const float*)d_in[10];

  char* ws = (char*)d_ws;
  size_t off = 0;
  auto alloc = [&](size_t bytes) {
    char* p = ws + off;
    off += (bytes + 255) & ~(size_t)255;
    return p;
  };
  unsigned short* xb = (unsigned short*)alloc(33554432ull * 2);
  unsigned short* Qb = (unsigned short*)alloc(33554432ull * 2);
  unsigned short* Kt = (unsigned short*)alloc(33554432ull * 2);
  unsigned short* Vt = (unsigned short*)alloc(33554432ull * 2);
  unsigned short* Wqkvt = (unsigned short*)alloc(3145728ull * 2);
  unsigned short* Wot = (unsigned short*)alloc(1048576ull * 2);
  unsigned short* Et = (unsigned short*)alloc(1048576ull * 2);
  unsigned short* Ft = (unsigned short*)alloc(1048576ull * 2);
  unsigned short* Kp = (unsigned short*)alloc(2097152ull * 2);
  unsigned short* VpT = (unsigned short*)alloc(2097152ull * 2);
  float* biasq = (float*)alloc(3072 * 4);
  (void)in_sizes; (void)n_in; (void)out_size; (void)ws_size;

  k_cvt_x<<<32768, 256, 0, stream>>>(x, xb);
  k_prep<<<24588, 256, 0, stream>>>(Wq, Wk, Wv, Wo, E, Fp, bq, bk, bv, Wqkvt, Wot, Et, Ft, biasq);
  k_gemm_qkv<<<dim3(12, 128), 512, 0, stream>>>(xb, Wqkvt, biasq, Qb, Kt, Vt);
  k_gemm_kpvp<<<dim3(8, 2, 16), 256, 0, stream>>>(Et, Ft, Kt, Vt, Kp, VpT);
  k_attn<<<dim3(64, 16, 8), 256, 0, stream>>>(Qb, Kp, VpT, xb);
  k_gemm_out<<<dim3(4, 128), 512, 0, stream>>>(xb, Wot, bo, (float*)d_out);
}